// Round 1
// baseline (4645.807 us; speedup 1.0000x reference)
//
#include <hip/hip_runtime.h>
#include <cstdint>

#define C_DIM 1024
#define T_DIM 2048
#define B_DIM 4
#define FFN_DIM 4096
#define NROWS (B_DIM * T_DIM)                 // 8192 rows (B*T)
#define NELEM ((size_t)NROWS * C_DIM)         // 8388608 elements per [B,T,C] buffer

// ---------------------------------------------------------------------------
// LayerNorm over last dim (C=1024). One block (256 thr) per row; float4/thread.
// ---------------------------------------------------------------------------
__global__ __launch_bounds__(256) void ln_kernel(const float* __restrict__ x,
                                                 const float* __restrict__ g,
                                                 const float* __restrict__ b,
                                                 float* __restrict__ y)
{
    int row = blockIdx.x;
    int tid = threadIdx.x;
    const float4* xr = (const float4*)(x + (size_t)row * C_DIM);
    float4 v = xr[tid];
    float s  = v.x + v.y + v.z + v.w;
    float s2 = v.x * v.x + v.y * v.y + v.z * v.z + v.w * v.w;
    for (int off = 32; off > 0; off >>= 1) {
        s  += __shfl_down(s,  off);
        s2 += __shfl_down(s2, off);
    }
    __shared__ float red[8];
    int lane = tid & 63, wid = tid >> 6;
    if (lane == 0) { red[wid] = s; red[4 + wid] = s2; }
    __syncthreads();
    s  = red[0] + red[1] + red[2] + red[3];
    s2 = red[4] + red[5] + red[6] + red[7];
    float mean = s * (1.0f / C_DIM);
    float var  = s2 * (1.0f / C_DIM) - mean * mean;
    float inv  = rsqrtf(var + 1e-5f);
    float4 gv = ((const float4*)g)[tid];
    float4 bv = ((const float4*)b)[tid];
    float4 o;
    o.x = (v.x - mean) * inv * gv.x + bv.x;
    o.y = (v.y - mean) * inv * gv.y + bv.y;
    o.z = (v.z - mean) * inv * gv.z + bv.z;
    o.w = (v.w - mean) * inv * gv.w + bv.w;
    ((float4*)(y + (size_t)row * C_DIM))[tid] = o;
}

// ---------------------------------------------------------------------------
// Token-shift mix: xk = hx + mk*(h - hx) with hx = h[t-1] (zero at t=0).
// Produces 2 or 3 mixed tensors in one pass. float4 per thread.
// ---------------------------------------------------------------------------
template<bool HASV>
__global__ __launch_bounds__(256) void mix_kernel(const float* __restrict__ h,
                                                  const float* __restrict__ mk,
                                                  const float* __restrict__ mv,
                                                  const float* __restrict__ mr,
                                                  float* __restrict__ xk,
                                                  float* __restrict__ xv,
                                                  float* __restrict__ xr)
{
    size_t i4 = (size_t)blockIdx.x * 256 + threadIdx.x;   // float4 index
    int c4 = (int)(i4 & (C_DIM / 4 - 1));
    size_t row = i4 >> 8;                                  // / (C_DIM/4)
    int t = (int)(row & (T_DIM - 1));
    float4 hv = ((const float4*)h)[i4];
    float4 hp = make_float4(0.f, 0.f, 0.f, 0.f);
    if (t != 0) hp = ((const float4*)h)[i4 - C_DIM / 4];

    float4 m1 = ((const float4*)mk)[c4];
    float4 o;
    o.x = hp.x + m1.x * (hv.x - hp.x);
    o.y = hp.y + m1.y * (hv.y - hp.y);
    o.z = hp.z + m1.z * (hv.z - hp.z);
    o.w = hp.w + m1.w * (hv.w - hp.w);
    ((float4*)xk)[i4] = o;

    if (HASV) {
        float4 m2 = ((const float4*)mv)[c4];
        o.x = hp.x + m2.x * (hv.x - hp.x);
        o.y = hp.y + m2.y * (hv.y - hp.y);
        o.z = hp.z + m2.z * (hv.z - hp.z);
        o.w = hp.w + m2.w * (hv.w - hp.w);
        ((float4*)xv)[i4] = o;
    }

    float4 m3 = ((const float4*)mr)[c4];
    o.x = hp.x + m3.x * (hv.x - hp.x);
    o.y = hp.y + m3.y * (hv.y - hp.y);
    o.z = hp.z + m3.z * (hv.z - hp.z);
    o.w = hp.w + m3.w * (hv.w - hp.w);
    ((float4*)xr)[i4] = o;
}

// ---------------------------------------------------------------------------
// TN SGEMM: Y[M,N] = epi( A[M,K] @ W[N,K]^T ).  128x128 tile, BK=8,
// 256 threads, 8x8 micro-tile per thread. All dims divide tiles exactly
// (M in {2048,8192}, N in {1024,4096}, K in {1024,4096}).
// Epilogues: 0=none 1=sigmoid 2=relu^2 3=X2+acc 4=X2+S*acc
// ---------------------------------------------------------------------------
#define EPI_NONE 0
#define EPI_SIG 1
#define EPI_RELU2 2
#define EPI_ADD 3
#define EPI_SCALEADD 4

template<int EPI>
__global__ __launch_bounds__(256, 2) void gemm_tn(const float* __restrict__ A,
                                                  const float* __restrict__ W,
                                                  float* __restrict__ Y,
                                                  const float* __restrict__ X2,
                                                  const float* __restrict__ S,
                                                  int N, int K)
{
    __shared__ float As[8][128];
    __shared__ float Bs[8][128];
    int tid = threadIdx.x;
    int m0 = blockIdx.y * 128, n0 = blockIdx.x * 128;
    int lr = tid >> 1;              // 0..127: tile row loaded by this thread
    int lc = (tid & 1) << 2;        // k offset 0 or 4 (float4)
    const float* Ap = A + (size_t)(m0 + lr) * K + lc;
    const float* Wp = W + (size_t)(n0 + lr) * K + lc;
    int tx = tid & 15, ty = tid >> 4;

    float acc[8][8];
#pragma unroll
    for (int i = 0; i < 8; ++i)
#pragma unroll
        for (int j = 0; j < 8; ++j) acc[i][j] = 0.f;

    for (int k0 = 0; k0 < K; k0 += 8) {
        float4 av = *(const float4*)(Ap + k0);
        float4 wv = *(const float4*)(Wp + k0);
        __syncthreads();
        As[lc + 0][lr] = av.x; As[lc + 1][lr] = av.y;
        As[lc + 2][lr] = av.z; As[lc + 3][lr] = av.w;
        Bs[lc + 0][lr] = wv.x; Bs[lc + 1][lr] = wv.y;
        Bs[lc + 2][lr] = wv.z; Bs[lc + 3][lr] = wv.w;
        __syncthreads();
#pragma unroll
        for (int k = 0; k < 8; ++k) {
            float a[8], b[8];
            *(float4*)&a[0] = *(const float4*)&As[k][ty * 8];
            *(float4*)&a[4] = *(const float4*)&As[k][ty * 8 + 4];
            *(float4*)&b[0] = *(const float4*)&Bs[k][tx * 8];
            *(float4*)&b[4] = *(const float4*)&Bs[k][tx * 8 + 4];
#pragma unroll
            for (int i = 0; i < 8; ++i)
#pragma unroll
                for (int j = 0; j < 8; ++j)
                    acc[i][j] = fmaf(a[i], b[j], acc[i][j]);
        }
    }

#pragma unroll
    for (int i = 0; i < 8; ++i) {
        int m = m0 + ty * 8 + i;
        size_t rowbase = (size_t)m * N + n0 + tx * 8;
#pragma unroll
        for (int h = 0; h < 2; ++h) {
            size_t idx = rowbase + h * 4;
            float r[4];
#pragma unroll
            for (int l = 0; l < 4; ++l) {
                float v = acc[i][h * 4 + l];
                if (EPI == EPI_SIG)        v = 1.0f / (1.0f + __expf(-v));
                else if (EPI == EPI_RELU2) { float rv = fmaxf(v, 0.0f); v = rv * rv; }
                else if (EPI == EPI_ADD)   v = X2[idx + l] + v;
                else if (EPI == EPI_SCALEADD) v = X2[idx + l] + S[idx + l] * v;
                r[l] = v;
            }
            float4 o; o.x = r[0]; o.y = r[1]; o.z = r[2]; o.w = r[3];
            *(float4*)(Y + idx) = o;
        }
    }
}

// ---------------------------------------------------------------------------
// WKV recurrence (numerically-stable log-space form, matches reference).
// One thread per (b,c) channel; sequential over T. Fuses rwkv = sr * wkv.
// ---------------------------------------------------------------------------
__global__ __launch_bounds__(64) void wkv_kernel(const float* __restrict__ k,
                                                 const float* __restrict__ v,
                                                 const float* __restrict__ sr,
                                                 const float* __restrict__ decay,
                                                 const float* __restrict__ first,
                                                 float* __restrict__ out)
{
    int idx = blockIdx.x * 64 + threadIdx.x;   // 0..B*C-1
    int c = idx & (C_DIM - 1);
    int b = idx >> 10;
    float w = -__expf(decay[c]);
    float u = first[c];
    size_t base = (size_t)b * T_DIM * C_DIM + c;
    float aa = 0.f, bb = 0.f, pp = -1e38f;
    for (int t = 0; t < T_DIM; ++t) {
        size_t off = base + (size_t)t * C_DIM;
        float kk = k[off];
        float vv = v[off];
        float ww = u + kk;
        float p  = fmaxf(pp, ww);
        float e1 = __expf(pp - p);
        float e2 = __expf(ww - p);
        float o  = (e1 * aa + e2 * vv) / (e1 * bb + e2);
        out[off] = sr[off] * o;
        float ww2 = pp + w;
        float p2  = fmaxf(ww2, kk);
        float e1b = __expf(ww2 - p2);
        float e2b = __expf(kk - p2);
        aa = e1b * aa + e2b * vv;
        bb = e1b * bb + e2b;
        pp = p2;
    }
}

// ---------------------------------------------------------------------------
// Orchestration. Workspace: 6 x NELEM floats = 192 MB.
//   A: h1 / h2 / kk-chunk   B: xk / sr / sr2   C: xv / rwkv
//   D: xr / xk2             E: k / xr2         F: v
// ---------------------------------------------------------------------------
extern "C" void kernel_launch(void* const* d_in, const int* in_sizes, int n_in,
                              void* d_out, int out_size, void* d_ws, size_t ws_size,
                              hipStream_t stream)
{
    const float* x          = (const float*)d_in[0];
    const float* ln1_w      = (const float*)d_in[1];
    const float* ln1_b      = (const float*)d_in[2];
    const float* ln2_w      = (const float*)d_in[3];
    const float* ln2_b      = (const float*)d_in[4];
    const float* time_decay = (const float*)d_in[5];
    const float* time_first = (const float*)d_in[6];
    const float* tmk        = (const float*)d_in[7];
    const float* tmv        = (const float*)d_in[8];
    const float* tmr        = (const float*)d_in[9];
    const float* att_kw     = (const float*)d_in[10];
    const float* att_vw     = (const float*)d_in[11];
    const float* att_rw     = (const float*)d_in[12];
    const float* att_ow     = (const float*)d_in[13];
    const float* f_tmk      = (const float*)d_in[14];
    const float* f_tmr      = (const float*)d_in[15];
    const float* f_kw       = (const float*)d_in[16];
    const float* f_rw       = (const float*)d_in[17];
    const float* f_vw       = (const float*)d_in[18];
    float* out = (float*)d_out;

    float* bufA = (float*)d_ws;
    float* bufB = bufA + NELEM;
    float* bufC = bufB + NELEM;
    float* bufD = bufC + NELEM;
    float* bufE = bufD + NELEM;
    float* bufF = bufE + NELEM;

    int mixGrid = (int)(NELEM / 4 / 256);       // 8192
    dim3 gC(C_DIM / 128, NROWS / 128);          // (8, 64) for N=1024 GEMMs

    // --- TimeMix ---
    ln_kernel<<<NROWS, 256, 0, stream>>>(x, ln1_w, ln1_b, bufA);
    mix_kernel<true><<<mixGrid, 256, 0, stream>>>(bufA, tmk, tmv, tmr, bufB, bufC, bufD);
    gemm_tn<EPI_NONE><<<gC, 256, 0, stream>>>(bufB, att_kw, bufE, nullptr, nullptr, C_DIM, C_DIM);
    gemm_tn<EPI_NONE><<<gC, 256, 0, stream>>>(bufC, att_vw, bufF, nullptr, nullptr, C_DIM, C_DIM);
    gemm_tn<EPI_SIG ><<<gC, 256, 0, stream>>>(bufD, att_rw, bufB, nullptr, nullptr, C_DIM, C_DIM);
    wkv_kernel<<<(B_DIM * C_DIM) / 64, 64, 0, stream>>>(bufE, bufF, bufB, time_decay, time_first, bufC);
    gemm_tn<EPI_ADD ><<<gC, 256, 0, stream>>>(bufC, att_ow, out, x, nullptr, C_DIM, C_DIM);

    // --- ChannelMix ---
    ln_kernel<<<NROWS, 256, 0, stream>>>(out, ln2_w, ln2_b, bufA);
    mix_kernel<false><<<mixGrid, 256, 0, stream>>>(bufA, f_tmk, nullptr, f_tmr, bufD, nullptr, bufE);
    gemm_tn<EPI_SIG><<<gC, 256, 0, stream>>>(bufE, f_rw, bufB, nullptr, nullptr, C_DIM, C_DIM);

    // FFN in 4 M-chunks of 2048 rows; kk chunk (2048x4096) reuses bufA.
    for (int mc = 0; mc < 4; ++mc) {
        size_t ro = (size_t)mc * 2048;
        dim3 g1(FFN_DIM / 128, 2048 / 128);     // (32, 16)
        gemm_tn<EPI_RELU2><<<g1, 256, 0, stream>>>(bufD + ro * C_DIM, f_kw, bufA,
                                                   nullptr, nullptr, FFN_DIM, C_DIM);
        dim3 g2(C_DIM / 128, 2048 / 128);       // (8, 16)
        gemm_tn<EPI_SCALEADD><<<g2, 256, 0, stream>>>(bufA, f_vw, out + ro * C_DIM,
                                                      out + ro * C_DIM, bufB + ro * C_DIM,
                                                      C_DIM, FFN_DIM);
    }
}

// Round 2
// 965.729 us; speedup vs baseline: 4.8107x; 4.8107x over previous
//
#include <hip/hip_runtime.h>
#include <cstdint>

#define C_DIM 1024
#define T_DIM 2048
#define B_DIM 4
#define FFN_DIM 4096
#define NROWS (B_DIM * T_DIM)                 // 8192 rows (B*T)
#define NELEM ((size_t)NROWS * C_DIM)
#define MB ((size_t)1 << 20)

typedef __bf16 bf16;
typedef __bf16 bf16x4 __attribute__((ext_vector_type(4)));
typedef __bf16 bf16x8 __attribute__((ext_vector_type(8)));
typedef float  floatx4 __attribute__((ext_vector_type(4)));

// async global->LDS, 16B per lane; LDS dest is wave-uniform base + lane*16
#define GLDS(g, l) __builtin_amdgcn_global_load_lds(                          \
    (const __attribute__((address_space(1))) void*)(g),                       \
    (__attribute__((address_space(3))) void*)(l), 16, 0, 0)

__device__ __forceinline__ void store_out(float* p, float v) { *p = v; }
__device__ __forceinline__ void store_out(bf16* p, float v)  { *p = (bf16)v; }

// ---------------------------------------------------------------------------
// fp32 -> bf16 conversion (weights), float4/thread
// ---------------------------------------------------------------------------
__global__ __launch_bounds__(256) void f2b_kernel(const float* __restrict__ s,
                                                  bf16* __restrict__ d, int n4)
{
    int i = blockIdx.x * 256 + threadIdx.x;
    if (i >= n4) return;
    float4 v = ((const float4*)s)[i];
    bf16x4 o = { (bf16)v.x, (bf16)v.y, (bf16)v.z, (bf16)v.w };
    ((bf16x4*)d)[i] = o;
}

// ---------------------------------------------------------------------------
// LayerNorm over last dim (C=1024). One block (256 thr) per row; float4/thread.
// ---------------------------------------------------------------------------
__global__ __launch_bounds__(256) void ln_kernel(const float* __restrict__ x,
                                                 const float* __restrict__ g,
                                                 const float* __restrict__ b,
                                                 float* __restrict__ y)
{
    int row = blockIdx.x;
    int tid = threadIdx.x;
    const float4* xr = (const float4*)(x + (size_t)row * C_DIM);
    float4 v = xr[tid];
    float s  = v.x + v.y + v.z + v.w;
    float s2 = v.x * v.x + v.y * v.y + v.z * v.z + v.w * v.w;
    for (int off = 32; off > 0; off >>= 1) {
        s  += __shfl_down(s,  off);
        s2 += __shfl_down(s2, off);
    }
    __shared__ float red[8];
    int lane = tid & 63, wid = tid >> 6;
    if (lane == 0) { red[wid] = s; red[4 + wid] = s2; }
    __syncthreads();
    s  = red[0] + red[1] + red[2] + red[3];
    s2 = red[4] + red[5] + red[6] + red[7];
    float mean = s * (1.0f / C_DIM);
    float var  = s2 * (1.0f / C_DIM) - mean * mean;
    float inv  = rsqrtf(var + 1e-5f);
    float4 gv = ((const float4*)g)[tid];
    float4 bv = ((const float4*)b)[tid];
    float4 o;
    o.x = (v.x - mean) * inv * gv.x + bv.x;
    o.y = (v.y - mean) * inv * gv.y + bv.y;
    o.z = (v.z - mean) * inv * gv.z + bv.z;
    o.w = (v.w - mean) * inv * gv.w + bv.w;
    ((float4*)(y + (size_t)row * C_DIM))[tid] = o;
}

// ---------------------------------------------------------------------------
// Token-shift mix -> bf16 GEMM operands. fp32 math, bf16 stores.
// ---------------------------------------------------------------------------
template<bool HASV>
__global__ __launch_bounds__(256) void mix_kernel(const float* __restrict__ h,
                                                  const float* __restrict__ mk,
                                                  const float* __restrict__ mv,
                                                  const float* __restrict__ mr,
                                                  bf16* __restrict__ xk,
                                                  bf16* __restrict__ xv,
                                                  bf16* __restrict__ xr)
{
    size_t i4 = (size_t)blockIdx.x * 256 + threadIdx.x;   // float4 index
    int c4 = (int)(i4 & (C_DIM / 4 - 1));
    size_t row = i4 >> 8;
    int t = (int)(row & (T_DIM - 1));
    float4 hv = ((const float4*)h)[i4];
    float4 hp = make_float4(0.f, 0.f, 0.f, 0.f);
    if (t != 0) hp = ((const float4*)h)[i4 - C_DIM / 4];

    float4 m1 = ((const float4*)mk)[c4];
    bf16x4 o;
    o.x = (bf16)(hp.x + m1.x * (hv.x - hp.x));
    o.y = (bf16)(hp.y + m1.y * (hv.y - hp.y));
    o.z = (bf16)(hp.z + m1.z * (hv.z - hp.z));
    o.w = (bf16)(hp.w + m1.w * (hv.w - hp.w));
    ((bf16x4*)xk)[i4] = o;

    if (HASV) {
        float4 m2 = ((const float4*)mv)[c4];
        o.x = (bf16)(hp.x + m2.x * (hv.x - hp.x));
        o.y = (bf16)(hp.y + m2.y * (hv.y - hp.y));
        o.z = (bf16)(hp.z + m2.z * (hv.z - hp.z));
        o.w = (bf16)(hp.w + m2.w * (hv.w - hp.w));
        ((bf16x4*)xv)[i4] = o;
    }

    float4 m3 = ((const float4*)mr)[c4];
    o.x = (bf16)(hp.x + m3.x * (hv.x - hp.x));
    o.y = (bf16)(hp.y + m3.y * (hv.y - hp.y));
    o.z = (bf16)(hp.z + m3.z * (hv.z - hp.z));
    o.w = (bf16)(hp.w + m3.w * (hv.w - hp.w));
    ((bf16x4*)xr)[i4] = o;
}

// ---------------------------------------------------------------------------
// bf16 MFMA TN GEMM (m97 recipe): Y[M,N] = epi( A[M,K] @ W[N,K]^T ).
// 128x128 tile, BK=32, 256 thr (4 waves, 2x2 of 64x64), 16x16x32 MFMA,
// global_load_lds width=16 staging, fp32 accumulate.
// Epilogues: 0=none 1=sigmoid 2=relu^2 3=X2+acc 4=X2+S*acc
// ---------------------------------------------------------------------------
#define EPI_NONE 0
#define EPI_SIG 1
#define EPI_RELU2 2
#define EPI_ADD 3
#define EPI_SCALEADD 4

template<int EPI, typename OutT>
__global__ __launch_bounds__(256) void gemm_bf16(const bf16* __restrict__ A,
                                                 const bf16* __restrict__ W,
                                                 OutT* __restrict__ Y,
                                                 const float* __restrict__ X2,
                                                 const bf16* __restrict__ S,
                                                 int N, int K)
{
    __shared__ unsigned short As[128 * 32];   // [row][k] bf16, 8 KB
    __shared__ unsigned short Bs[128 * 32];

    int tid = threadIdx.x;
    int m0 = blockIdx.y * 128, n0 = blockIdx.x * 128;

    // staging: thread tid loads 16B = 8 bf16 at (row=tid>>2, k8=(tid&3)*8); two row-chunks
    const bf16* Ag = A + (size_t)(m0 + (tid >> 2)) * K + (tid & 3) * 8;
    const bf16* Wg = W + (size_t)(n0 + (tid >> 2)) * K + (tid & 3) * 8;
    size_t rowK = (size_t)64 * K;
    int wv = tid >> 6;
    unsigned short* AsW0 = As + wv * 512;            // wave-uniform LDS bases
    unsigned short* AsW1 = As + 2048 + wv * 512;
    unsigned short* BsW0 = Bs + wv * 512;
    unsigned short* BsW1 = Bs + 2048 + wv * 512;

    int ln = tid & 63;
    int wm = (wv & 1) * 64, wn = (wv >> 1) * 64;
    int aoff = (wm + (ln & 15)) * 32 + (ln >> 4) * 8;   // A-frag: row=lane&15, k=quad*8+j
    int boff = (wn + (ln & 15)) * 32 + (ln >> 4) * 8;

    floatx4 acc[4][4] = {};

    for (int k0 = 0; k0 < K; k0 += 32) {
        if (k0) __syncthreads();                 // LDS consumed by prev iter's ds_reads
        GLDS(Ag + k0,        AsW0);
        GLDS(Ag + k0 + rowK, AsW1);
        GLDS(Wg + k0,        BsW0);
        GLDS(Wg + k0 + rowK, BsW1);
        __syncthreads();                         // vmcnt(0) drain + barrier

        bf16x8 a[4], b[4];
#pragma unroll
        for (int i = 0; i < 4; ++i) a[i] = *(const bf16x8*)(As + aoff + i * 512);
#pragma unroll
        for (int j = 0; j < 4; ++j) b[j] = *(const bf16x8*)(Bs + boff + j * 512);
#pragma unroll
        for (int i = 0; i < 4; ++i)
#pragma unroll
            for (int j = 0; j < 4; ++j)
                acc[i][j] = __builtin_amdgcn_mfma_f32_16x16x32_bf16(a[i], b[j], acc[i][j], 0, 0, 0);
    }

    // C/D layout (m89-verified): col = lane&15, row = (lane>>4)*4 + reg
    int row0 = (ln >> 4) * 4;
    int colb = n0 + wn + (ln & 15);
#pragma unroll
    for (int i = 0; i < 4; ++i) {
        int gm = m0 + wm + i * 16 + row0;
#pragma unroll
        for (int j = 0; j < 4; ++j) {
            int gn = colb + j * 16;
#pragma unroll
            for (int r = 0; r < 4; ++r) {
                size_t idx = (size_t)(gm + r) * N + gn;
                float v = acc[i][j][r];
                if (EPI == EPI_SIG)        v = 1.0f / (1.0f + __expf(-v));
                else if (EPI == EPI_RELU2) { float t = fmaxf(v, 0.0f); v = t * t; }
                else if (EPI == EPI_ADD)   v = X2[idx] + v;
                else if (EPI == EPI_SCALEADD) v = X2[idx] + (float)S[idx] * v;
                store_out(&Y[idx], v);
            }
        }
    }
}

// ---------------------------------------------------------------------------
// WKV recurrence (log-space stable, matches reference). fp32 in, fuses
// rwkv = sigmoid(r) * wkv, writes bf16 for the ow GEMM.
// ---------------------------------------------------------------------------
__global__ __launch_bounds__(64) void wkv_kernel(const float* __restrict__ k,
                                                 const float* __restrict__ v,
                                                 const float* __restrict__ sr,
                                                 const float* __restrict__ decay,
                                                 const float* __restrict__ first,
                                                 bf16* __restrict__ out)
{
    int idx = blockIdx.x * 64 + threadIdx.x;   // 0..B*C-1
    int c = idx & (C_DIM - 1);
    int b = idx >> 10;
    float w = -__expf(decay[c]);
    float u = first[c];
    size_t base = (size_t)b * T_DIM * C_DIM + c;
    float aa = 0.f, bb = 0.f, pp = -1e38f;
    for (int t = 0; t < T_DIM; ++t) {
        size_t off = base + (size_t)t * C_DIM;
        float kk = k[off];
        float vv = v[off];
        float ww = u + kk;
        float p  = fmaxf(pp, ww);
        float e1 = __expf(pp - p);
        float e2 = __expf(ww - p);
        float o  = (e1 * aa + e2 * vv) / (e1 * bb + e2);
        out[off] = (bf16)(sr[off] * o);
        float ww2 = pp + w;
        float p2  = fmaxf(ww2, kk);
        float e1b = __expf(ww2 - p2);
        float e2b = __expf(kk - p2);
        aa = e1b * aa + e2b * vv;
        bb = e1b * bb + e2b;
        pp = p2;
    }
}

// ---------------------------------------------------------------------------
// Orchestration. Workspace (byte offsets, 170 MiB peak):
//   [0,26M)    bf16 weights: kw vw rw ow (2M each) | f_kw 8M | f_rw 2M | f_vw 8M
//   [26,74M)   bf16 acts: xk xv xr (16M) -> rwkv | xk2 xr2 sr2
//   [74,170M)  fp32 acts: h|k (32M), v (32M), sr (32M) -> h2, kk_b(64M@106M)
// ---------------------------------------------------------------------------
extern "C" void kernel_launch(void* const* d_in, const int* in_sizes, int n_in,
                              void* d_out, int out_size, void* d_ws, size_t ws_size,
                              hipStream_t stream)
{
    const float* x          = (const float*)d_in[0];
    const float* ln1_w      = (const float*)d_in[1];
    const float* ln1_b      = (const float*)d_in[2];
    const float* ln2_w      = (const float*)d_in[3];
    const float* ln2_b      = (const float*)d_in[4];
    const float* time_decay = (const float*)d_in[5];
    const float* time_first = (const float*)d_in[6];
    const float* tmk        = (const float*)d_in[7];
    const float* tmv        = (const float*)d_in[8];
    const float* tmr        = (const float*)d_in[9];
    const float* att_kw     = (const float*)d_in[10];
    const float* att_vw     = (const float*)d_in[11];
    const float* att_rw     = (const float*)d_in[12];
    const float* att_ow     = (const float*)d_in[13];
    const float* f_tmk      = (const float*)d_in[14];
    const float* f_tmr      = (const float*)d_in[15];
    const float* f_kw       = (const float*)d_in[16];
    const float* f_rw       = (const float*)d_in[17];
    const float* f_vw       = (const float*)d_in[18];
    float* out = (float*)d_out;

    char* W8 = (char*)d_ws;
    bf16* kw_b  = (bf16*)(W8 + 0 * MB);
    bf16* vw_b  = (bf16*)(W8 + 2 * MB);
    bf16* rw_b  = (bf16*)(W8 + 4 * MB);
    bf16* ow_b  = (bf16*)(W8 + 6 * MB);
    bf16* fkw_b = (bf16*)(W8 + 8 * MB);
    bf16* frw_b = (bf16*)(W8 + 16 * MB);
    bf16* fvw_b = (bf16*)(W8 + 18 * MB);

    bf16*  xk_b   = (bf16*)(W8 + 26 * MB);
    bf16*  xv_b   = (bf16*)(W8 + 42 * MB);
    bf16*  xr_b   = (bf16*)(W8 + 58 * MB);
    bf16*  rwkv_b = xk_b;                       // reuse after k-GEMM
    bf16*  xk2_b  = (bf16*)(W8 + 26 * MB);      // reuse after ow-GEMM
    bf16*  xr2_b  = (bf16*)(W8 + 42 * MB);
    bf16*  sr2_b  = (bf16*)(W8 + 58 * MB);
    float* h      = (float*)(W8 + 74 * MB);     // dies before k-GEMM writes here
    float* kbuf   = (float*)(W8 + 74 * MB);
    float* vbuf   = (float*)(W8 + 106 * MB);
    float* srb    = (float*)(W8 + 138 * MB);
    float* h2     = (float*)(W8 + 74 * MB);
    bf16*  kk_b   = (bf16*)(W8 + 106 * MB);     // 64 MiB [106,170)

    // weight conversion (every call; ws is re-poisoned by harness)
    int nC = C_DIM * C_DIM / 4, nF = FFN_DIM * C_DIM / 4;
    f2b_kernel<<<(nC + 255) / 256, 256, 0, stream>>>(att_kw, kw_b, nC);
    f2b_kernel<<<(nC + 255) / 256, 256, 0, stream>>>(att_vw, vw_b, nC);
    f2b_kernel<<<(nC + 255) / 256, 256, 0, stream>>>(att_rw, rw_b, nC);
    f2b_kernel<<<(nC + 255) / 256, 256, 0, stream>>>(att_ow, ow_b, nC);
    f2b_kernel<<<(nF + 255) / 256, 256, 0, stream>>>(f_kw, fkw_b, nF);
    f2b_kernel<<<(nC + 255) / 256, 256, 0, stream>>>(f_rw, frw_b, nC);
    f2b_kernel<<<(nF + 255) / 256, 256, 0, stream>>>(f_vw, fvw_b, nF);

    int mixGrid = (int)(NELEM / 4 / 256);
    dim3 gC(C_DIM / 128, NROWS / 128);          // (8, 64)
    dim3 gF(FFN_DIM / 128, NROWS / 128);        // (32, 64)

    // --- TimeMix ---
    ln_kernel<<<NROWS, 256, 0, stream>>>(x, ln1_w, ln1_b, h);
    mix_kernel<true><<<mixGrid, 256, 0, stream>>>(h, tmk, tmv, tmr, xk_b, xv_b, xr_b);
    gemm_bf16<EPI_NONE, float><<<gC, 256, 0, stream>>>(xk_b, kw_b, kbuf, nullptr, nullptr, C_DIM, C_DIM);
    gemm_bf16<EPI_NONE, float><<<gC, 256, 0, stream>>>(xv_b, vw_b, vbuf, nullptr, nullptr, C_DIM, C_DIM);
    gemm_bf16<EPI_SIG,  float><<<gC, 256, 0, stream>>>(xr_b, rw_b, srb,  nullptr, nullptr, C_DIM, C_DIM);
    wkv_kernel<<<(B_DIM * C_DIM) / 64, 64, 0, stream>>>(kbuf, vbuf, srb, time_decay, time_first, rwkv_b);
    gemm_bf16<EPI_ADD,  float><<<gC, 256, 0, stream>>>(rwkv_b, ow_b, out, x, nullptr, C_DIM, C_DIM);

    // --- ChannelMix ---
    ln_kernel<<<NROWS, 256, 0, stream>>>(out, ln2_w, ln2_b, h2);
    mix_kernel<false><<<mixGrid, 256, 0, stream>>>(h2, f_tmk, nullptr, f_tmr, xk2_b, nullptr, xr2_b);
    gemm_bf16<EPI_SIG,   bf16><<<gC, 256, 0, stream>>>(xr2_b, frw_b, sr2_b, nullptr, nullptr, C_DIM, C_DIM);
    gemm_bf16<EPI_RELU2, bf16><<<gF, 256, 0, stream>>>(xk2_b, fkw_b, kk_b, nullptr, nullptr, FFN_DIM, C_DIM);
    gemm_bf16<EPI_SCALEADD, float><<<gC, 256, 0, stream>>>(kk_b, fvw_b, out, out, sr2_b, C_DIM, FFN_DIM);
}

// Round 3
// 599.602 us; speedup vs baseline: 7.7482x; 1.6106x over previous
//
#include <hip/hip_runtime.h>
#include <cstdint>

#define C_DIM 1024
#define T_DIM 2048
#define B_DIM 4
#define FFN_DIM 4096
#define NROWS (B_DIM * T_DIM)                 // 8192 rows (B*T)
#define NELEM ((size_t)NROWS * C_DIM)
#define MB ((size_t)1 << 20)
#define NSEG 32
#define SEGL (T_DIM / NSEG)                   // 64

typedef __bf16 bf16;
typedef __bf16 bf16x4 __attribute__((ext_vector_type(4)));
typedef __bf16 bf16x8 __attribute__((ext_vector_type(8)));
typedef float  floatx4 __attribute__((ext_vector_type(4)));

// async global->LDS, 16B per lane; LDS dest is wave-uniform base + lane*16
#define GLDS(g, l) __builtin_amdgcn_global_load_lds(                          \
    (const __attribute__((address_space(1))) void*)(g),                       \
    (__attribute__((address_space(3))) void*)(l), 16, 0, 0)

__device__ __forceinline__ void store_out(float* p, float v) { *p = v; }
__device__ __forceinline__ void store_out(bf16* p, float v)  { *p = (bf16)v; }

// ---------------------------------------------------------------------------
// fp32 -> bf16 conversion (weights), float4/thread
// ---------------------------------------------------------------------------
__global__ __launch_bounds__(256) void f2b_kernel(const float* __restrict__ s,
                                                  bf16* __restrict__ d, int n4)
{
    int i = blockIdx.x * 256 + threadIdx.x;
    if (i >= n4) return;
    float4 v = ((const float4*)s)[i];
    bf16x4 o = { (bf16)v.x, (bf16)v.y, (bf16)v.z, (bf16)v.w };
    ((bf16x4*)d)[i] = o;
}

// ---------------------------------------------------------------------------
// LayerNorm over last dim (C=1024). One block (256 thr) per row; float4/thread.
// ---------------------------------------------------------------------------
__global__ __launch_bounds__(256) void ln_kernel(const float* __restrict__ x,
                                                 const float* __restrict__ g,
                                                 const float* __restrict__ b,
                                                 float* __restrict__ y)
{
    int row = blockIdx.x;
    int tid = threadIdx.x;
    const float4* xr = (const float4*)(x + (size_t)row * C_DIM);
    float4 v = xr[tid];
    float s  = v.x + v.y + v.z + v.w;
    float s2 = v.x * v.x + v.y * v.y + v.z * v.z + v.w * v.w;
    for (int off = 32; off > 0; off >>= 1) {
        s  += __shfl_down(s,  off);
        s2 += __shfl_down(s2, off);
    }
    __shared__ float red[8];
    int lane = tid & 63, wid = tid >> 6;
    if (lane == 0) { red[wid] = s; red[4 + wid] = s2; }
    __syncthreads();
    s  = red[0] + red[1] + red[2] + red[3];
    s2 = red[4] + red[5] + red[6] + red[7];
    float mean = s * (1.0f / C_DIM);
    float var  = s2 * (1.0f / C_DIM) - mean * mean;
    float inv  = rsqrtf(var + 1e-5f);
    float4 gv = ((const float4*)g)[tid];
    float4 bv = ((const float4*)b)[tid];
    float4 o;
    o.x = (v.x - mean) * inv * gv.x + bv.x;
    o.y = (v.y - mean) * inv * gv.y + bv.y;
    o.z = (v.z - mean) * inv * gv.z + bv.z;
    o.w = (v.w - mean) * inv * gv.w + bv.w;
    ((float4*)(y + (size_t)row * C_DIM))[tid] = o;
}

// ---------------------------------------------------------------------------
// Token-shift mix -> bf16 GEMM operands. fp32 math, bf16 stores.
// ---------------------------------------------------------------------------
template<bool HASV>
__global__ __launch_bounds__(256) void mix_kernel(const float* __restrict__ h,
                                                  const float* __restrict__ mk,
                                                  const float* __restrict__ mv,
                                                  const float* __restrict__ mr,
                                                  bf16* __restrict__ xk,
                                                  bf16* __restrict__ xv,
                                                  bf16* __restrict__ xr)
{
    size_t i4 = (size_t)blockIdx.x * 256 + threadIdx.x;   // float4 index
    int c4 = (int)(i4 & (C_DIM / 4 - 1));
    size_t row = i4 >> 8;
    int t = (int)(row & (T_DIM - 1));
    float4 hv = ((const float4*)h)[i4];
    float4 hp = make_float4(0.f, 0.f, 0.f, 0.f);
    if (t != 0) hp = ((const float4*)h)[i4 - C_DIM / 4];

    float4 m1 = ((const float4*)mk)[c4];
    bf16x4 o;
    o.x = (bf16)(hp.x + m1.x * (hv.x - hp.x));
    o.y = (bf16)(hp.y + m1.y * (hv.y - hp.y));
    o.z = (bf16)(hp.z + m1.z * (hv.z - hp.z));
    o.w = (bf16)(hp.w + m1.w * (hv.w - hp.w));
    ((bf16x4*)xk)[i4] = o;

    if (HASV) {
        float4 m2 = ((const float4*)mv)[c4];
        o.x = (bf16)(hp.x + m2.x * (hv.x - hp.x));
        o.y = (bf16)(hp.y + m2.y * (hv.y - hp.y));
        o.z = (bf16)(hp.z + m2.z * (hv.z - hp.z));
        o.w = (bf16)(hp.w + m2.w * (hv.w - hp.w));
        ((bf16x4*)xv)[i4] = o;
    }

    float4 m3 = ((const float4*)mr)[c4];
    o.x = (bf16)(hp.x + m3.x * (hv.x - hp.x));
    o.y = (bf16)(hp.y + m3.y * (hv.y - hp.y));
    o.z = (bf16)(hp.z + m3.z * (hv.z - hp.z));
    o.w = (bf16)(hp.w + m3.w * (hv.w - hp.w));
    ((bf16x4*)xr)[i4] = o;
}

// ---------------------------------------------------------------------------
// bf16 MFMA TN GEMM (m97 recipe): Y[M,N] = epi( A[M,K] @ W[N,K]^T ).
// 128x128 tile, BK=32, 256 thr (4 waves, 2x2 of 64x64), 16x16x32 MFMA,
// global_load_lds width=16 staging, fp32 accumulate.
// Epilogues: 0=none 1=sigmoid 2=relu^2 3=X2+acc 4=X2+S*acc
// ---------------------------------------------------------------------------
#define EPI_NONE 0
#define EPI_SIG 1
#define EPI_RELU2 2
#define EPI_ADD 3
#define EPI_SCALEADD 4

template<int EPI, typename OutT>
__global__ __launch_bounds__(256) void gemm_bf16(const bf16* __restrict__ A,
                                                 const bf16* __restrict__ W,
                                                 OutT* __restrict__ Y,
                                                 const float* __restrict__ X2,
                                                 const bf16* __restrict__ S,
                                                 int N, int K)
{
    __shared__ unsigned short As[128 * 32];   // [row][k] bf16, 8 KB
    __shared__ unsigned short Bs[128 * 32];

    int tid = threadIdx.x;
    int m0 = blockIdx.y * 128, n0 = blockIdx.x * 128;

    // staging: thread tid loads 16B = 8 bf16 at (row=tid>>2, k8=(tid&3)*8); two row-chunks
    const bf16* Ag = A + (size_t)(m0 + (tid >> 2)) * K + (tid & 3) * 8;
    const bf16* Wg = W + (size_t)(n0 + (tid >> 2)) * K + (tid & 3) * 8;
    size_t rowK = (size_t)64 * K;
    int wv = tid >> 6;
    unsigned short* AsW0 = As + wv * 512;            // wave-uniform LDS bases
    unsigned short* AsW1 = As + 2048 + wv * 512;
    unsigned short* BsW0 = Bs + wv * 512;
    unsigned short* BsW1 = Bs + 2048 + wv * 512;

    int ln = tid & 63;
    int wm = (wv & 1) * 64, wn = (wv >> 1) * 64;
    int aoff = (wm + (ln & 15)) * 32 + (ln >> 4) * 8;   // A-frag: row=lane&15, k=quad*8+j
    int boff = (wn + (ln & 15)) * 32 + (ln >> 4) * 8;

    floatx4 acc[4][4] = {};

    for (int k0 = 0; k0 < K; k0 += 32) {
        if (k0) __syncthreads();                 // LDS consumed by prev iter's ds_reads
        GLDS(Ag + k0,        AsW0);
        GLDS(Ag + k0 + rowK, AsW1);
        GLDS(Wg + k0,        BsW0);
        GLDS(Wg + k0 + rowK, BsW1);
        __syncthreads();                         // vmcnt(0) drain + barrier

        bf16x8 a[4], b[4];
#pragma unroll
        for (int i = 0; i < 4; ++i) a[i] = *(const bf16x8*)(As + aoff + i * 512);
#pragma unroll
        for (int j = 0; j < 4; ++j) b[j] = *(const bf16x8*)(Bs + boff + j * 512);
#pragma unroll
        for (int i = 0; i < 4; ++i)
#pragma unroll
            for (int j = 0; j < 4; ++j)
                acc[i][j] = __builtin_amdgcn_mfma_f32_16x16x32_bf16(a[i], b[j], acc[i][j], 0, 0, 0);
    }

    // C/D layout (m89-verified): col = lane&15, row = (lane>>4)*4 + reg
    int row0 = (ln >> 4) * 4;
    int colb = n0 + wn + (ln & 15);
#pragma unroll
    for (int i = 0; i < 4; ++i) {
        int gm = m0 + wm + i * 16 + row0;
#pragma unroll
        for (int j = 0; j < 4; ++j) {
            int gn = colb + j * 16;
#pragma unroll
            for (int r = 0; r < 4; ++r) {
                size_t idx = (size_t)(gm + r) * N + gn;
                float v = acc[i][j][r];
                if (EPI == EPI_SIG)        v = 1.0f / (1.0f + __expf(-v));
                else if (EPI == EPI_RELU2) { float t = fmaxf(v, 0.0f); v = t * t; }
                else if (EPI == EPI_ADD)   v = X2[idx] + v;
                else if (EPI == EPI_SCALEADD) v = X2[idx] + (float)S[idx] * v;
                store_out(&Y[idx], v);
            }
        }
    }
}

// ---------------------------------------------------------------------------
// WKV segmented scan. Affine recurrence S_t = e^w * S_{t-1} + e^{k_t}(v_t,1),
// state kept stabilized as (aa, bb, pp) meaning (aa,bb)*e^pp.
// Pass 1: per-(b,seg,c) segment summary beta from zero state.
// Pass 2: per-(b,c) sequential combine over NSEG segments -> incoming states.
// Pass 3: per-(b,seg,c) replay emitting outputs (fused sr*wkv, bf16 store).
// ---------------------------------------------------------------------------
__global__ __launch_bounds__(256) void wkv_seg(const float* __restrict__ k,
                                               const float* __restrict__ v,
                                               const float* __restrict__ decay,
                                               float* __restrict__ sa,
                                               float* __restrict__ sb,
                                               float* __restrict__ sp)
{
    int idx = blockIdx.x * 256 + threadIdx.x;   // (b*NSEG+seg)*C + c
    int c   = idx & (C_DIM - 1);
    int bs  = idx >> 10;
    int seg = bs & (NSEG - 1);
    int b   = bs >> 5;
    float w = -__expf(decay[c]);
    size_t base = ((size_t)b * T_DIM + (size_t)seg * SEGL) * C_DIM + c;
    float aa = 0.f, bb = 0.f, pp = -1e38f;
    for (int t = 0; t < SEGL; ++t) {
        size_t off = base + (size_t)t * C_DIM;
        float kk = k[off], vv = v[off];
        float ww2 = pp + w;
        float p2  = fmaxf(ww2, kk);
        float e1  = __expf(ww2 - p2);
        float e2  = __expf(kk - p2);
        aa = e1 * aa + e2 * vv;
        bb = e1 * bb + e2;
        pp = p2;
    }
    sa[idx] = aa; sb[idx] = bb; sp[idx] = pp;
}

__global__ __launch_bounds__(256) void wkv_comb(const float* __restrict__ sa,
                                                const float* __restrict__ sb,
                                                const float* __restrict__ sp,
                                                const float* __restrict__ decay,
                                                float* __restrict__ ia,
                                                float* __restrict__ ib,
                                                float* __restrict__ ip)
{
    int idx = blockIdx.x * 256 + threadIdx.x;   // b*C + c, total B*C
    int c = idx & (C_DIM - 1);
    int b = idx >> 10;
    float wL = -__expf(decay[c]) * (float)SEGL;
    float aa = 0.f, bb = 0.f, pp = -1e38f;
    size_t base = (size_t)b * NSEG * C_DIM + c;
    for (int j = 0; j < NSEG; ++j) {
        size_t o = base + (size_t)j * C_DIM;
        ia[o] = aa; ib[o] = bb; ip[o] = pp;     // incoming state for segment j
        float a_s = sa[o], b_s = sb[o], p_s = sp[o];
        float pd = pp + wL;                     // alpha-decayed exponent
        float pn = fmaxf(pd, p_s);
        float e1 = __expf(pd - pn);
        float e2 = __expf(p_s - pn);
        aa = e1 * aa + e2 * a_s;
        bb = e1 * bb + e2 * b_s;
        pp = pn;
    }
}

__global__ __launch_bounds__(256) void wkv_out(const float* __restrict__ k,
                                               const float* __restrict__ v,
                                               const float* __restrict__ sr,
                                               const float* __restrict__ decay,
                                               const float* __restrict__ first,
                                               const float* __restrict__ ia,
                                               const float* __restrict__ ib,
                                               const float* __restrict__ ip,
                                               bf16* __restrict__ out)
{
    int idx = blockIdx.x * 256 + threadIdx.x;   // (b*NSEG+seg)*C + c
    int c   = idx & (C_DIM - 1);
    int bs  = idx >> 10;
    int seg = bs & (NSEG - 1);
    int b   = bs >> 5;
    float w = -__expf(decay[c]);
    float u = first[c];
    float aa = ia[idx], bb = ib[idx], pp = ip[idx];
    size_t base = ((size_t)b * T_DIM + (size_t)seg * SEGL) * C_DIM + c;
    for (int t = 0; t < SEGL; ++t) {
        size_t off = base + (size_t)t * C_DIM;
        float kk = k[off], vv = v[off];
        float ww = u + kk;
        float p  = fmaxf(pp, ww);
        float e1 = __expf(pp - p);
        float e2 = __expf(ww - p);
        float o  = (e1 * aa + e2 * vv) / (e1 * bb + e2);
        out[off] = (bf16)(sr[off] * o);
        float ww2 = pp + w;
        float p2  = fmaxf(ww2, kk);
        float e1b = __expf(ww2 - p2);
        float e2b = __expf(kk - p2);
        aa = e1b * aa + e2b * vv;
        bb = e1b * bb + e2b;
        pp = p2;
    }
}

// ---------------------------------------------------------------------------
// Orchestration. Workspace (byte offsets, 173 MiB peak):
//   [0,26M)    bf16 weights: kw vw rw ow (2M each) | f_kw 8M | f_rw 2M | f_vw 8M
//   [26,74M)   bf16 acts: xk xv xr (16M) -> rwkv | xk2 xr2 sr2
//   [74,170M)  fp32 acts: h|k (32M), v (32M), sr (32M) -> h2, kk_b(64M@106M)
//   [170,173M) WKV scan scratch: 6 x 512 KiB
// ---------------------------------------------------------------------------
extern "C" void kernel_launch(void* const* d_in, const int* in_sizes, int n_in,
                              void* d_out, int out_size, void* d_ws, size_t ws_size,
                              hipStream_t stream)
{
    const float* x          = (const float*)d_in[0];
    const float* ln1_w      = (const float*)d_in[1];
    const float* ln1_b      = (const float*)d_in[2];
    const float* ln2_w      = (const float*)d_in[3];
    const float* ln2_b      = (const float*)d_in[4];
    const float* time_decay = (const float*)d_in[5];
    const float* time_first = (const float*)d_in[6];
    const float* tmk        = (const float*)d_in[7];
    const float* tmv        = (const float*)d_in[8];
    const float* tmr        = (const float*)d_in[9];
    const float* att_kw     = (const float*)d_in[10];
    const float* att_vw     = (const float*)d_in[11];
    const float* att_rw     = (const float*)d_in[12];
    const float* att_ow     = (const float*)d_in[13];
    const float* f_tmk      = (const float*)d_in[14];
    const float* f_tmr      = (const float*)d_in[15];
    const float* f_kw       = (const float*)d_in[16];
    const float* f_rw       = (const float*)d_in[17];
    const float* f_vw       = (const float*)d_in[18];
    float* out = (float*)d_out;

    char* W8 = (char*)d_ws;
    bf16* kw_b  = (bf16*)(W8 + 0 * MB);
    bf16* vw_b  = (bf16*)(W8 + 2 * MB);
    bf16* rw_b  = (bf16*)(W8 + 4 * MB);
    bf16* ow_b  = (bf16*)(W8 + 6 * MB);
    bf16* fkw_b = (bf16*)(W8 + 8 * MB);
    bf16* frw_b = (bf16*)(W8 + 16 * MB);
    bf16* fvw_b = (bf16*)(W8 + 18 * MB);

    bf16*  xk_b   = (bf16*)(W8 + 26 * MB);
    bf16*  xv_b   = (bf16*)(W8 + 42 * MB);
    bf16*  xr_b   = (bf16*)(W8 + 58 * MB);
    bf16*  rwkv_b = xk_b;                       // reuse after k-GEMM
    bf16*  xk2_b  = (bf16*)(W8 + 26 * MB);      // reuse after ow-GEMM
    bf16*  xr2_b  = (bf16*)(W8 + 42 * MB);
    bf16*  sr2_b  = (bf16*)(W8 + 58 * MB);
    float* h      = (float*)(W8 + 74 * MB);     // dies before k-GEMM writes here
    float* kbuf   = (float*)(W8 + 74 * MB);
    float* vbuf   = (float*)(W8 + 106 * MB);
    float* srb    = (float*)(W8 + 138 * MB);
    float* h2     = (float*)(W8 + 74 * MB);
    bf16*  kk_b   = (bf16*)(W8 + 106 * MB);     // 64 MiB [106,170)

    size_t KB512 = (size_t)512 * 1024;
    float* sc_a = (float*)(W8 + 170 * MB);
    float* sc_b = (float*)(W8 + 170 * MB + 1 * KB512);
    float* sc_p = (float*)(W8 + 170 * MB + 2 * KB512);
    float* in_a = (float*)(W8 + 170 * MB + 3 * KB512);
    float* in_b = (float*)(W8 + 170 * MB + 4 * KB512);
    float* in_p = (float*)(W8 + 170 * MB + 5 * KB512);

    // weight conversion (every call; ws is re-poisoned by harness)
    int nC = C_DIM * C_DIM / 4, nF = FFN_DIM * C_DIM / 4;
    f2b_kernel<<<(nC + 255) / 256, 256, 0, stream>>>(att_kw, kw_b, nC);
    f2b_kernel<<<(nC + 255) / 256, 256, 0, stream>>>(att_vw, vw_b, nC);
    f2b_kernel<<<(nC + 255) / 256, 256, 0, stream>>>(att_rw, rw_b, nC);
    f2b_kernel<<<(nC + 255) / 256, 256, 0, stream>>>(att_ow, ow_b, nC);
    f2b_kernel<<<(nF + 255) / 256, 256, 0, stream>>>(f_kw, fkw_b, nF);
    f2b_kernel<<<(nC + 255) / 256, 256, 0, stream>>>(f_rw, frw_b, nC);
    f2b_kernel<<<(nF + 255) / 256, 256, 0, stream>>>(f_vw, fvw_b, nF);

    int mixGrid = (int)(NELEM / 4 / 256);
    dim3 gC(C_DIM / 128, NROWS / 128);          // (8, 64)
    dim3 gF(FFN_DIM / 128, NROWS / 128);        // (32, 64)
    int segGrid = B_DIM * NSEG * C_DIM / 256;   // 512

    // --- TimeMix ---
    ln_kernel<<<NROWS, 256, 0, stream>>>(x, ln1_w, ln1_b, h);
    mix_kernel<true><<<mixGrid, 256, 0, stream>>>(h, tmk, tmv, tmr, xk_b, xv_b, xr_b);
    gemm_bf16<EPI_NONE, float><<<gC, 256, 0, stream>>>(xk_b, kw_b, kbuf, nullptr, nullptr, C_DIM, C_DIM);
    gemm_bf16<EPI_NONE, float><<<gC, 256, 0, stream>>>(xv_b, vw_b, vbuf, nullptr, nullptr, C_DIM, C_DIM);
    gemm_bf16<EPI_SIG,  float><<<gC, 256, 0, stream>>>(xr_b, rw_b, srb,  nullptr, nullptr, C_DIM, C_DIM);
    wkv_seg<<<segGrid, 256, 0, stream>>>(kbuf, vbuf, time_decay, sc_a, sc_b, sc_p);
    wkv_comb<<<B_DIM * C_DIM / 256, 256, 0, stream>>>(sc_a, sc_b, sc_p, time_decay, in_a, in_b, in_p);
    wkv_out<<<segGrid, 256, 0, stream>>>(kbuf, vbuf, srb, time_decay, time_first,
                                         in_a, in_b, in_p, rwkv_b);
    gemm_bf16<EPI_ADD,  float><<<gC, 256, 0, stream>>>(rwkv_b, ow_b, out, x, nullptr, C_DIM, C_DIM);

    // --- ChannelMix ---
    ln_kernel<<<NROWS, 256, 0, stream>>>(out, ln2_w, ln2_b, h2);
    mix_kernel<false><<<mixGrid, 256, 0, stream>>>(h2, f_tmk, nullptr, f_tmr, xk2_b, nullptr, xr2_b);
    gemm_bf16<EPI_SIG,   bf16><<<gC, 256, 0, stream>>>(xr2_b, frw_b, sr2_b, nullptr, nullptr, C_DIM, C_DIM);
    gemm_bf16<EPI_RELU2, bf16><<<gF, 256, 0, stream>>>(xk2_b, fkw_b, kk_b, nullptr, nullptr, FFN_DIM, C_DIM);
    gemm_bf16<EPI_SCALEADD, float><<<gC, 256, 0, stream>>>(kk_b, fvw_b, out, out, sr2_b, C_DIM, FFN_DIM);
}

// Round 4
// 562.447 us; speedup vs baseline: 8.2600x; 1.0661x over previous
//
#include <hip/hip_runtime.h>
#include <cstdint>

#define C_DIM 1024
#define T_DIM 2048
#define B_DIM 4
#define FFN_DIM 4096
#define NROWS (B_DIM * T_DIM)                 // 8192 rows (B*T)
#define NELEM ((size_t)NROWS * C_DIM)
#define MB ((size_t)1 << 20)
#define NSEG 32
#define SEGL (T_DIM / NSEG)                   // 64

typedef __bf16 bf16;
typedef __bf16 bf16x4 __attribute__((ext_vector_type(4)));
typedef __bf16 bf16x8 __attribute__((ext_vector_type(8)));
typedef float  floatx4 __attribute__((ext_vector_type(4)));

// async global->LDS, 16B per lane; LDS dest is wave-uniform base + lane*16
#define GLDS(g, l) __builtin_amdgcn_global_load_lds(                          \
    (const __attribute__((address_space(1))) void*)(g),                       \
    (__attribute__((address_space(3))) void*)(l), 16, 0, 0)

__device__ __forceinline__ void store_out(float* p, float v) { *p = v; }
__device__ __forceinline__ void store_out(bf16* p, float v)  { *p = (bf16)v; }

// ---------------------------------------------------------------------------
// All 7 weight fp32->bf16 conversions in ONE dispatch.
// ---------------------------------------------------------------------------
struct W7 {
    const float* s[7];
    bf16*        d[7];
    int          cum[8];   // cumulative float4 counts, cum[7] = total
};

__global__ __launch_bounds__(256) void f2b7_kernel(W7 w)
{
    int id = blockIdx.x * 256 + threadIdx.x;
    int seg = 0;
#pragma unroll
    for (int j = 1; j < 7; ++j) if (id >= w.cum[j]) seg = j;
    int i = id - w.cum[seg];
    float4 v = ((const float4*)w.s[seg])[i];
    bf16x4 o = { (bf16)v.x, (bf16)v.y, (bf16)v.z, (bf16)v.w };
    ((bf16x4*)w.d[seg])[i] = o;
}

// ---------------------------------------------------------------------------
// Fused LayerNorm + token-shift mix. One block per row t; computes LN stats
// for rows t and t-1 (recompute, memory-bound), emits bf16 mixed operands.
// hx = LN(x[t-1]) (zero row at t==0, matching reference pad-before-shift).
// ---------------------------------------------------------------------------
template<bool HASV>
__global__ __launch_bounds__(256) void lnmix_kernel(const float* __restrict__ x,
                                                    const float* __restrict__ g,
                                                    const float* __restrict__ b,
                                                    const float* __restrict__ mk,
                                                    const float* __restrict__ mv,
                                                    const float* __restrict__ mr,
                                                    bf16* __restrict__ xk,
                                                    bf16* __restrict__ xv,
                                                    bf16* __restrict__ xr)
{
    int row = blockIdx.x;
    int t   = row & (T_DIM - 1);
    int tid = threadIdx.x;
    size_t i4 = (size_t)row * 256 + tid;

    float4 v  = ((const float4*)x)[i4];
    float4 vp = make_float4(0.f, 0.f, 0.f, 0.f);
    if (t != 0) vp = ((const float4*)x)[i4 - 256];

    float s   = v.x + v.y + v.z + v.w;
    float s2  = v.x * v.x + v.y * v.y + v.z * v.z + v.w * v.w;
    float sp  = vp.x + vp.y + vp.z + vp.w;
    float sp2 = vp.x * vp.x + vp.y * vp.y + vp.z * vp.z + vp.w * vp.w;
    for (int off = 32; off > 0; off >>= 1) {
        s   += __shfl_down(s,   off);
        s2  += __shfl_down(s2,  off);
        sp  += __shfl_down(sp,  off);
        sp2 += __shfl_down(sp2, off);
    }
    __shared__ float red[16];
    int lane = tid & 63, wid = tid >> 6;
    if (lane == 0) { red[wid] = s; red[4 + wid] = s2; red[8 + wid] = sp; red[12 + wid] = sp2; }
    __syncthreads();
    s   = red[0] + red[1] + red[2] + red[3];
    s2  = red[4] + red[5] + red[6] + red[7];
    sp  = red[8] + red[9] + red[10] + red[11];
    sp2 = red[12] + red[13] + red[14] + red[15];

    float mean  = s * (1.0f / C_DIM);
    float inv   = rsqrtf(s2 * (1.0f / C_DIM) - mean * mean + 1e-5f);
    float meanp = sp * (1.0f / C_DIM);
    float invp  = rsqrtf(sp2 * (1.0f / C_DIM) - meanp * meanp + 1e-5f);

    float4 gv = ((const float4*)g)[tid];
    float4 bv = ((const float4*)b)[tid];
    float4 hv, hp;
    hv.x = (v.x - mean) * inv * gv.x + bv.x;
    hv.y = (v.y - mean) * inv * gv.y + bv.y;
    hv.z = (v.z - mean) * inv * gv.z + bv.z;
    hv.w = (v.w - mean) * inv * gv.w + bv.w;
    if (t != 0) {
        hp.x = (vp.x - meanp) * invp * gv.x + bv.x;
        hp.y = (vp.y - meanp) * invp * gv.y + bv.y;
        hp.z = (vp.z - meanp) * invp * gv.z + bv.z;
        hp.w = (vp.w - meanp) * invp * gv.w + bv.w;
    } else {
        hp = make_float4(0.f, 0.f, 0.f, 0.f);
    }

    float4 m1 = ((const float4*)mk)[tid];
    bf16x4 o;
    o.x = (bf16)(hp.x + m1.x * (hv.x - hp.x));
    o.y = (bf16)(hp.y + m1.y * (hv.y - hp.y));
    o.z = (bf16)(hp.z + m1.z * (hv.z - hp.z));
    o.w = (bf16)(hp.w + m1.w * (hv.w - hp.w));
    ((bf16x4*)xk)[i4] = o;

    if (HASV) {
        float4 m2 = ((const float4*)mv)[tid];
        o.x = (bf16)(hp.x + m2.x * (hv.x - hp.x));
        o.y = (bf16)(hp.y + m2.y * (hv.y - hp.y));
        o.z = (bf16)(hp.z + m2.z * (hv.z - hp.z));
        o.w = (bf16)(hp.w + m2.w * (hv.w - hp.w));
        ((bf16x4*)xv)[i4] = o;
    }

    float4 m3 = ((const float4*)mr)[tid];
    o.x = (bf16)(hp.x + m3.x * (hv.x - hp.x));
    o.y = (bf16)(hp.y + m3.y * (hv.y - hp.y));
    o.z = (bf16)(hp.z + m3.z * (hv.z - hp.z));
    o.w = (bf16)(hp.w + m3.w * (hv.w - hp.w));
    ((bf16x4*)xr)[i4] = o;
}

// ---------------------------------------------------------------------------
// bf16 MFMA TN GEMM: Y[M,N] = epi( A[M,K] @ W[N,K]^T ), M = 8192 fixed.
// 128x128 tile, BK=32, 256 thr (4 waves, 2x2 of 64x64), 16x16x32 MFMA.
// LDS cell (row r, k-quad q) stored at r*32 + ((q + (r>>1))&3)*8 ushorts:
// conflict-free ds_read_b128 (8-lane phases hit all 32 banks once) while
// keeping global_load_lds lane-contiguous dest + coalesced 64B row chunks.
// 1-D grid, XCD-aware: id&7 selects an n-stripe -> W stripe L2-resident.
// Epilogues: 0=none 1=sigmoid 2=relu^2 3=X2+acc 4=X2+S*acc
// ---------------------------------------------------------------------------
#define EPI_NONE 0
#define EPI_SIG 1
#define EPI_RELU2 2
#define EPI_ADD 3
#define EPI_SCALEADD 4

template<int EPI, typename OutT>
__global__ __launch_bounds__(256) void gemm_bf16(const bf16* __restrict__ A,
                                                 const bf16* __restrict__ W,
                                                 OutT* __restrict__ Y,
                                                 const float* __restrict__ X2,
                                                 const bf16* __restrict__ S,
                                                 int N, int K)
{
    __shared__ unsigned short As[128 * 32];   // 8 KB, swizzled layout
    __shared__ unsigned short Bs[128 * 32];

    int tid = threadIdx.x;
    // XCD-aware tile mapping
    int ntn    = N >> 7;            // n-tiles (8 or 32)
    int stride = ntn >> 3;          // n-tiles per XCD stripe (1 or 4)
    int id  = blockIdx.x;
    int sq  = id >> 3;
    int n_t = (id & 7) * stride + (sq % stride);
    int m_t = sq / stride;
    int m0 = m_t * 128, n0 = n_t * 128;

    // staging: lane writes LDS at (wave base + lane*16B); source swizzled quad
    int r0  = tid >> 2;                               // rows 0..63 (chunk0)
    int qsw = ((tid & 3) - ((r0 >> 1) & 3)) & 3;      // rotated k-quad
    const bf16* Ag = A + (size_t)(m0 + r0) * K + qsw * 8;
    const bf16* Wg = W + (size_t)(n0 + r0) * K + qsw * 8;
    size_t rowK = (size_t)64 * K;
    int wv = tid >> 6;
    unsigned short* AsW0 = As + wv * 512;             // wave-uniform LDS bases
    unsigned short* AsW1 = As + 2048 + wv * 512;
    unsigned short* BsW0 = Bs + wv * 512;
    unsigned short* BsW1 = Bs + 2048 + wv * 512;

    int ln = tid & 63;
    int wm = (wv & 1) * 64, wn = (wv >> 1) * 64;
    int ra0 = wm + (ln & 15);
    int rb0 = wn + (ln & 15);
    int qa  = ln >> 4;
    int abase = ra0 * 32 + (((qa + (ra0 >> 1)) & 3) * 8);  // swizzled read addr
    int bbase = rb0 * 32 + (((qa + (rb0 >> 1)) & 3) * 8);

    floatx4 acc[4][4] = {};

    for (int k0 = 0; k0 < K; k0 += 32) {
        if (k0) __syncthreads();                 // LDS consumed by prev iter
        GLDS(Ag + k0,        AsW0);
        GLDS(Ag + k0 + rowK, AsW1);
        GLDS(Wg + k0,        BsW0);
        GLDS(Wg + k0 + rowK, BsW1);
        __syncthreads();                         // vmcnt(0) drain + barrier

        bf16x8 a[4], b[4];
#pragma unroll
        for (int i = 0; i < 4; ++i) a[i] = *(const bf16x8*)(As + abase + i * 512);
#pragma unroll
        for (int j = 0; j < 4; ++j) b[j] = *(const bf16x8*)(Bs + bbase + j * 512);
#pragma unroll
        for (int i = 0; i < 4; ++i)
#pragma unroll
            for (int j = 0; j < 4; ++j)
                acc[i][j] = __builtin_amdgcn_mfma_f32_16x16x32_bf16(a[i], b[j], acc[i][j], 0, 0, 0);
    }

    // C/D layout (m89-verified): col = lane&15, row = (lane>>4)*4 + reg
    int row0 = (ln >> 4) * 4;
    int colb = n0 + wn + (ln & 15);
#pragma unroll
    for (int i = 0; i < 4; ++i) {
        int gm = m0 + wm + i * 16 + row0;
#pragma unroll
        for (int j = 0; j < 4; ++j) {
            int gn = colb + j * 16;
#pragma unroll
            for (int r = 0; r < 4; ++r) {
                size_t idx = (size_t)(gm + r) * N + gn;
                float v = acc[i][j][r];
                if (EPI == EPI_SIG)        v = 1.0f / (1.0f + __expf(-v));
                else if (EPI == EPI_RELU2) { float t = fmaxf(v, 0.0f); v = t * t; }
                else if (EPI == EPI_ADD)   v = X2[idx] + v;
                else if (EPI == EPI_SCALEADD) v = X2[idx] + (float)S[idx] * v;
                store_out(&Y[idx], v);
            }
        }
    }
}

// ---------------------------------------------------------------------------
// WKV segmented scan (3 passes), log-space stabilized state (aa,bb)*e^pp.
// ---------------------------------------------------------------------------
__global__ __launch_bounds__(256) void wkv_seg(const float* __restrict__ k,
                                               const float* __restrict__ v,
                                               const float* __restrict__ decay,
                                               float* __restrict__ sa,
                                               float* __restrict__ sb,
                                               float* __restrict__ sp)
{
    int idx = blockIdx.x * 256 + threadIdx.x;   // (b*NSEG+seg)*C + c
    int c   = idx & (C_DIM - 1);
    int bs  = idx >> 10;
    int seg = bs & (NSEG - 1);
    int b   = bs >> 5;
    float w = -__expf(decay[c]);
    size_t base = ((size_t)b * T_DIM + (size_t)seg * SEGL) * C_DIM + c;
    float aa = 0.f, bb = 0.f, pp = -1e38f;
    for (int t = 0; t < SEGL; ++t) {
        size_t off = base + (size_t)t * C_DIM;
        float kk = k[off], vv = v[off];
        float ww2 = pp + w;
        float p2  = fmaxf(ww2, kk);
        float e1  = __expf(ww2 - p2);
        float e2  = __expf(kk - p2);
        aa = e1 * aa + e2 * vv;
        bb = e1 * bb + e2;
        pp = p2;
    }
    sa[idx] = aa; sb[idx] = bb; sp[idx] = pp;
}

__global__ __launch_bounds__(256) void wkv_comb(const float* __restrict__ sa,
                                                const float* __restrict__ sb,
                                                const float* __restrict__ sp,
                                                const float* __restrict__ decay,
                                                float* __restrict__ ia,
                                                float* __restrict__ ib,
                                                float* __restrict__ ip)
{
    int idx = blockIdx.x * 256 + threadIdx.x;   // b*C + c
    int c = idx & (C_DIM - 1);
    int b = idx >> 10;
    float wL = -__expf(decay[c]) * (float)SEGL;
    float aa = 0.f, bb = 0.f, pp = -1e38f;
    size_t base = (size_t)b * NSEG * C_DIM + c;
    for (int j = 0; j < NSEG; ++j) {
        size_t o = base + (size_t)j * C_DIM;
        ia[o] = aa; ib[o] = bb; ip[o] = pp;     // incoming state for segment j
        float a_s = sa[o], b_s = sb[o], p_s = sp[o];
        float pd = pp + wL;
        float pn = fmaxf(pd, p_s);
        float e1 = __expf(pd - pn);
        float e2 = __expf(p_s - pn);
        aa = e1 * aa + e2 * a_s;
        bb = e1 * bb + e2 * b_s;
        pp = pn;
    }
}

__global__ __launch_bounds__(256) void wkv_out(const float* __restrict__ k,
                                               const float* __restrict__ v,
                                               const bf16* __restrict__ sr,
                                               const float* __restrict__ decay,
                                               const float* __restrict__ first,
                                               const float* __restrict__ ia,
                                               const float* __restrict__ ib,
                                               const float* __restrict__ ip,
                                               bf16* __restrict__ out)
{
    int idx = blockIdx.x * 256 + threadIdx.x;   // (b*NSEG+seg)*C + c
    int c   = idx & (C_DIM - 1);
    int bs  = idx >> 10;
    int seg = bs & (NSEG - 1);
    int b   = bs >> 5;
    float w = -__expf(decay[c]);
    float u = first[c];
    float aa = ia[idx], bb = ib[idx], pp = ip[idx];
    size_t base = ((size_t)b * T_DIM + (size_t)seg * SEGL) * C_DIM + c;
    for (int t = 0; t < SEGL; ++t) {
        size_t off = base + (size_t)t * C_DIM;
        float kk = k[off], vv = v[off];
        float ww = u + kk;
        float p  = fmaxf(pp, ww);
        float e1 = __expf(pp - p);
        float e2 = __expf(ww - p);
        float o  = (e1 * aa + e2 * vv) / (e1 * bb + e2);
        out[off] = (bf16)((float)sr[off] * o);
        float ww2 = pp + w;
        float p2  = fmaxf(ww2, kk);
        float e1b = __expf(ww2 - p2);
        float e2b = __expf(kk - p2);
        aa = e1b * aa + e2b * vv;
        bb = e1b * bb + e2b;
        pp = p2;
    }
}

// ---------------------------------------------------------------------------
// Orchestration. Workspace (byte offsets, 173 MiB peak):
//   [0,26M)    bf16 weights
//   [26,74M)   bf16 acts: xk xv xr -> rwkv | xk2 xr2 sr2
//   [74,170M)  fp32 k (32M), v (32M), sr_b bf16 (16M @138M), kk_b (64M @106M)
//   [170,173M) WKV scan scratch: 6 x 512 KiB
// ---------------------------------------------------------------------------
extern "C" void kernel_launch(void* const* d_in, const int* in_sizes, int n_in,
                              void* d_out, int out_size, void* d_ws, size_t ws_size,
                              hipStream_t stream)
{
    const float* x          = (const float*)d_in[0];
    const float* ln1_w      = (const float*)d_in[1];
    const float* ln1_b      = (const float*)d_in[2];
    const float* ln2_w      = (const float*)d_in[3];
    const float* ln2_b      = (const float*)d_in[4];
    const float* time_decay = (const float*)d_in[5];
    const float* time_first = (const float*)d_in[6];
    const float* tmk        = (const float*)d_in[7];
    const float* tmv        = (const float*)d_in[8];
    const float* tmr        = (const float*)d_in[9];
    const float* att_kw     = (const float*)d_in[10];
    const float* att_vw     = (const float*)d_in[11];
    const float* att_rw     = (const float*)d_in[12];
    const float* att_ow     = (const float*)d_in[13];
    const float* f_tmk      = (const float*)d_in[14];
    const float* f_tmr      = (const float*)d_in[15];
    const float* f_kw       = (const float*)d_in[16];
    const float* f_rw       = (const float*)d_in[17];
    const float* f_vw       = (const float*)d_in[18];
    float* out = (float*)d_out;

    char* W8 = (char*)d_ws;
    bf16* kw_b  = (bf16*)(W8 + 0 * MB);
    bf16* vw_b  = (bf16*)(W8 + 2 * MB);
    bf16* rw_b  = (bf16*)(W8 + 4 * MB);
    bf16* ow_b  = (bf16*)(W8 + 6 * MB);
    bf16* fkw_b = (bf16*)(W8 + 8 * MB);
    bf16* frw_b = (bf16*)(W8 + 16 * MB);
    bf16* fvw_b = (bf16*)(W8 + 18 * MB);

    bf16*  xk_b   = (bf16*)(W8 + 26 * MB);
    bf16*  xv_b   = (bf16*)(W8 + 42 * MB);
    bf16*  xr_b   = (bf16*)(W8 + 58 * MB);
    bf16*  rwkv_b = xk_b;
    bf16*  xk2_b  = (bf16*)(W8 + 26 * MB);
    bf16*  xr2_b  = (bf16*)(W8 + 42 * MB);
    bf16*  sr2_b  = (bf16*)(W8 + 58 * MB);
    float* kbuf   = (float*)(W8 + 74 * MB);
    float* vbuf   = (float*)(W8 + 106 * MB);
    bf16*  srb_b  = (bf16*)(W8 + 138 * MB);     // 16 MiB
    bf16*  kk_b   = (bf16*)(W8 + 106 * MB);     // 64 MiB, after wkv consumes vbuf? NO:
    // kk_b overlaps vbuf region; kk is written only AFTER wkv_out has consumed
    // kbuf/vbuf (ChannelMix phase), so the overlap is safe.

    size_t KB512 = (size_t)512 * 1024;
    float* sc_a = (float*)(W8 + 170 * MB);
    float* sc_b = (float*)(W8 + 170 * MB + 1 * KB512);
    float* sc_p = (float*)(W8 + 170 * MB + 2 * KB512);
    float* in_a = (float*)(W8 + 170 * MB + 3 * KB512);
    float* in_b = (float*)(W8 + 170 * MB + 4 * KB512);
    float* in_p = (float*)(W8 + 170 * MB + 5 * KB512);

    // single-dispatch weight conversion
    int nC4 = C_DIM * C_DIM / 4, nF4 = FFN_DIM * C_DIM / 4;
    W7 w7;
    const float* srcs[7] = { att_kw, att_vw, att_rw, att_ow, f_kw, f_rw, f_vw };
    bf16*        dsts[7] = { kw_b, vw_b, rw_b, ow_b, fkw_b, frw_b, fvw_b };
    int          cnts[7] = { nC4, nC4, nC4, nC4, nF4, nC4, nF4 };
    int cum = 0;
    for (int i = 0; i < 7; ++i) { w7.s[i] = srcs[i]; w7.d[i] = dsts[i]; w7.cum[i] = cum; cum += cnts[i]; }
    w7.cum[7] = cum;                                   // 3407872, /256 = 13312
    f2b7_kernel<<<cum / 256, 256, 0, stream>>>(w7);

    dim3 gC(8 * 64);                            // N=1024 GEMMs, 1-D XCD-swizzled
    dim3 gF(32 * 64);                           // N=4096 GEMM
    int segGrid = B_DIM * NSEG * C_DIM / 256;   // 512

    // --- TimeMix ---
    lnmix_kernel<true><<<NROWS, 256, 0, stream>>>(x, ln1_w, ln1_b, tmk, tmv, tmr,
                                                  xk_b, xv_b, xr_b);
    gemm_bf16<EPI_NONE, float><<<gC, 256, 0, stream>>>(xk_b, kw_b, kbuf, nullptr, nullptr, C_DIM, C_DIM);
    gemm_bf16<EPI_NONE, float><<<gC, 256, 0, stream>>>(xv_b, vw_b, vbuf, nullptr, nullptr, C_DIM, C_DIM);
    gemm_bf16<EPI_SIG,  bf16 ><<<gC, 256, 0, stream>>>(xr_b, rw_b, srb_b, nullptr, nullptr, C_DIM, C_DIM);
    wkv_seg<<<segGrid, 256, 0, stream>>>(kbuf, vbuf, time_decay, sc_a, sc_b, sc_p);
    wkv_comb<<<B_DIM * C_DIM / 256, 256, 0, stream>>>(sc_a, sc_b, sc_p, time_decay, in_a, in_b, in_p);
    wkv_out<<<segGrid, 256, 0, stream>>>(kbuf, vbuf, srb_b, time_decay, time_first,
                                         in_a, in_b, in_p, rwkv_b);
    gemm_bf16<EPI_ADD,  float><<<gC, 256, 0, stream>>>(rwkv_b, ow_b, out, x, nullptr, C_DIM, C_DIM);

    // --- ChannelMix ---
    lnmix_kernel<false><<<NROWS, 256, 0, stream>>>(out, ln2_w, ln2_b, f_tmk, nullptr, f_tmr,
                                                   xk2_b, nullptr, xr2_b);
    gemm_bf16<EPI_SIG,   bf16><<<gC, 256, 0, stream>>>(xr2_b, frw_b, sr2_b, nullptr, nullptr, C_DIM, C_DIM);
    gemm_bf16<EPI_RELU2, bf16><<<gF, 256, 0, stream>>>(xk2_b, fkw_b, kk_b, nullptr, nullptr, FFN_DIM, C_DIM);
    gemm_bf16<EPI_SCALEADD, float><<<gC, 256, 0, stream>>>(kk_b, fvw_b, out, out, sr2_b, C_DIM, FFN_DIM);
}